// Round 3
// baseline (2324.106 us; speedup 1.0000x reference)
//
#include <hip/hip_runtime.h>

#define HIDDEN 256
#define K_CODES 8192
#define N_TOK 32768           // 8 * 4096
#define MT 64                 // tokens per block
#define NT 64                 // codes per chunk
#define KT 32                 // k per LDS tile
#define ZST_ELEMS 8388608     // 8*4096*256

// ---------------- Kernel A: numpy-pairwise row sum-of-squares ----------------
// Emulates np.sum(x*x, axis=1) for 256-wide rows bit-exactly:
// n=256 -> pairwise split into two 128-blocks; each block is numpy's 8-way
// unrolled base case; products rounded separately (fp contract OFF).
__global__ void np_norms_kernel(const float* __restrict__ x, float* __restrict__ out,
                                int nrows) {
#pragma clang fp contract(off)
    int row = blockIdx.x * 256 + threadIdx.x;
    if (row >= nrows) return;
    const float4* q = (const float4*)(x + (size_t)row * HIDDEN);
    float s = 0.0f;
    for (int h = 0; h < 2; ++h) {            // two 128-element blocks
        const float4* p = q + h * 32;
        float4 a = p[0], b = p[1];
        float r0 = a.x * a.x, r1 = a.y * a.y, r2 = a.z * a.z, r3 = a.w * a.w;
        float r4 = b.x * b.x, r5 = b.y * b.y, r6 = b.z * b.z, r7 = b.w * b.w;
        for (int i = 1; i < 16; ++i) {
            a = p[2 * i]; b = p[2 * i + 1];
            r0 += a.x * a.x; r1 += a.y * a.y; r2 += a.z * a.z; r3 += a.w * a.w;
            r4 += b.x * b.x; r5 += b.y * b.y; r6 += b.z * b.z; r7 += b.w * b.w;
        }
        float blk = ((r0 + r1) + (r2 + r3)) + ((r4 + r5) + (r6 + r7));
        s = (h == 0) ? blk : (s + blk);
    }
    out[row] = s;
}

// ---------------- Kernel B: fp32 distance GEMM + argmin (np-exact scores) ---
// score = fl( fl(zn_t - 2*M_tk) + ne_k ), M_tk = ascending-k fused-FMA chain
// (matches BLAS sgemm single-accumulator microkernel). 2*M is exact.
__global__ __launch_bounds__(256, 2) void dist_argmin_kernel(
    const float* __restrict__ z, const float* __restrict__ emb,
    const float* __restrict__ ne, const float* __restrict__ zn,
    float* __restrict__ idx_out) {
#pragma clang fp contract(off)
    __shared__ float zt[KT][MT + 4];   // k-major, stride 68 floats
    __shared__ float et[KT][NT + 4];

    const int tid = threadIdx.x;
    const int tx  = tid & 15;          // code group 0..15
    const int ty  = tid >> 4;          // token group 0..15
    const int m0  = blockIdx.x * MT;

    const float4* z4 = (const float4*)z;
    const float4* e4 = (const float4*)emb;

    float zni[4];
    #pragma unroll
    for (int i = 0; i < 4; ++i) zni[i] = zn[m0 + ty * 4 + i];

    float tmin[4] = {3.4e38f, 3.4e38f, 3.4e38f, 3.4e38f};
    int   tidx[4] = {0, 0, 0, 0};

    for (int c0 = 0; c0 < K_CODES; c0 += NT) {
        float acc[4][4] = {};
        for (int k0 = 0; k0 < HIDDEN; k0 += KT) {
            __syncthreads();
            const int k0f = k0 >> 2;
            #pragma unroll
            for (int r = 0; r < 2; ++r) {
                int uu  = tid + 256 * r;
                int row = uu >> 3;
                int q   = uu & 7;
                float4 v = z4[(size_t)(m0 + row) * 64 + k0f + q];
                float4 w = e4[(size_t)(c0 + row) * 64 + k0f + q];
                float* vp = (float*)&v;
                float* wp = (float*)&w;
                #pragma unroll
                for (int j = 0; j < 4; ++j) {
                    zt[q * 4 + j][row] = vp[j];
                    et[q * 4 + j][row] = wp[j];
                }
            }
            __syncthreads();
            #pragma unroll
            for (int kk = 0; kk < KT; ++kk) {
                float a[4], b[4];
                *(float4*)a = *(const float4*)&zt[kk][ty * 4];
                *(float4*)b = *(const float4*)&et[kk][tx * 4];
                #pragma unroll
                for (int i = 0; i < 4; ++i)
                    #pragma unroll
                    for (int j = 0; j < 4; ++j)
                        acc[i][j] = __builtin_fmaf(a[i], b[j], acc[i][j]);
            }
        }
        // np-exact scores; ascending code order keeps first-min on ties
        #pragma unroll
        for (int j = 0; j < 4; ++j) {
            int   code = c0 + tx * 4 + j;
            float nej  = ne[code];
            #pragma unroll
            for (int i = 0; i < 4; ++i) {
                float t1 = zni[i] - 2.0f * acc[i][j];   // 2*acc exact; one rounding
                float s  = t1 + nej;                    // second rounding
                if (s < tmin[i]) { tmin[i] = s; tidx[i] = code; }
            }
        }
    }

    // reduce across 16 tx lanes per token; bit-equal ties -> lower index
    #pragma unroll
    for (int i = 0; i < 4; ++i) {
        float m  = tmin[i];
        int   bi = tidx[i];
        #pragma unroll
        for (int off = 1; off < 16; off <<= 1) {
            float om = __shfl_xor(m,  off, 64);
            int   oi = __shfl_xor(bi, off, 64);
            if (om < m || (om == m && oi < bi)) { m = om; bi = oi; }
        }
        if (tx == 0) idx_out[m0 + ty * 4 + i] = (float)bi;
    }
}

// ---------------- Kernel C: gather + straight-through + loss partials -------
__global__ void epilogue_kernel(const float* __restrict__ z, const float* __restrict__ emb,
                                const float* __restrict__ idxf, float* __restrict__ zst,
                                float* __restrict__ loss_accum) {
    int t4    = blockIdx.x * 256 + threadIdx.x;
    int token = t4 >> 6;
    int k4    = t4 & 63;
    int idx   = (int)idxf[token];

    float4 zv = ((const float4*)z)[t4];
    float4 ev = ((const float4*)emb)[(size_t)idx * 64 + k4];

    float dx = ev.x - zv.x, dy = ev.y - zv.y, dz = ev.z - zv.z, dw = ev.w - zv.w;
    float4 o = { zv.x + dx, zv.y + dy, zv.z + dz, zv.w + dw };
    ((float4*)zst)[t4] = o;

    float p = dx * dx + dy * dy + dz * dz + dw * dw;
    #pragma unroll
    for (int off = 32; off; off >>= 1) p += __shfl_down(p, off, 64);

    __shared__ float wsum[4];
    int lane = threadIdx.x & 63, w = threadIdx.x >> 6;
    if (lane == 0) wsum[w] = p;
    __syncthreads();
    if (threadIdx.x == 0)
        atomicAdd(loss_accum, wsum[0] + wsum[1] + wsum[2] + wsum[3]);
}

__global__ void finalize_kernel(const float* __restrict__ loss_accum,
                                float* __restrict__ out_losses) {
    float m = loss_accum[0] * (1.0f / (float)ZST_ELEMS);
    out_losses[0] = m;   // codebook_loss
    out_losses[1] = m;   // commit_loss (identical forward value)
}

// ---------------- launch ----------------
extern "C" void kernel_launch(void* const* d_in, const int* in_sizes, int n_in,
                              void* d_out, int out_size, void* d_ws, size_t ws_size,
                              hipStream_t stream) {
    const float* z   = (const float*)d_in[0];   // [8,4096,256]
    const float* emb = (const float*)d_in[1];   // [8192,256]

    float* out    = (float*)d_out;
    float* zst    = out;                        // 8388608
    float* idxf   = out + ZST_ELEMS;            // 32768
    float* losses = out + ZST_ELEMS + N_TOK;    // 2

    float* ne         = (float*)d_ws;           // 8192
    float* zn         = ne + K_CODES;           // 32768
    float* loss_accum = zn + N_TOK;             // 1

    hipMemsetAsync(loss_accum, 0, sizeof(float), stream);
    np_norms_kernel<<<K_CODES / 256, 256, 0, stream>>>(emb, ne, K_CODES);
    np_norms_kernel<<<N_TOK / 256, 256, 0, stream>>>(z, zn, N_TOK);
    dist_argmin_kernel<<<N_TOK / MT, 256, 0, stream>>>(z, emb, ne, zn, idxf);
    epilogue_kernel<<<(ZST_ELEMS / 4) / 256, 256, 0, stream>>>(z, emb, idxf, zst, loss_accum);
    finalize_kernel<<<1, 1, 0, stream>>>(loss_accum, losses);
}

// Round 4
// 1606.020 us; speedup vs baseline: 1.4471x; 1.4471x over previous
//
#include <hip/hip_runtime.h>

#define HIDDEN 256
#define K_CODES 8192
#define N_TOK 32768           // 8 * 4096
#define ZST_ELEMS 8388608     // 8*4096*256
#define NBLK 64               // code-dim blocks in MFMA gemm (8192/128)
#define MARGIN 1.0e-3f        // >> worst-case (split-bf16 + np-rounding) score error ~2e-4

using short8 = __attribute__((ext_vector_type(8))) short;   // 8 bf16 (4 VGPRs)
using f32x4  = __attribute__((ext_vector_type(4))) float;   // MFMA C/D frag

// ---------- deterministic RNE fp32->bf16 ----------
__device__ __forceinline__ unsigned short f2bf(float f) {
    unsigned int u = __float_as_uint(f);
    return (unsigned short)((u + 0x7fffu + ((u >> 16) & 1u)) >> 16);
}
__device__ __forceinline__ float bf2f(unsigned short h) {
    return __uint_as_float(((unsigned int)h) << 16);
}

__device__ __forceinline__ void gl2lds16(const void* g, void* l) {
    __builtin_amdgcn_global_load_lds(
        (const __attribute__((address_space(1))) unsigned int*)g,
        (__attribute__((address_space(3))) unsigned int*)l, 16, 0, 0);
}

// ---------------- numpy-pairwise row sum-of-squares (R2-proven exact) -------
__global__ void np_norms_kernel(const float* __restrict__ x, float* __restrict__ out,
                                int nrows) {
#pragma clang fp contract(off)
    int row = blockIdx.x * 256 + threadIdx.x;
    if (row >= nrows) return;
    const float4* q = (const float4*)(x + (size_t)row * HIDDEN);
    float s = 0.0f;
    for (int h = 0; h < 2; ++h) {
        const float4* p = q + h * 32;
        float4 a = p[0], b = p[1];
        float r0 = a.x * a.x, r1 = a.y * a.y, r2 = a.z * a.z, r3 = a.w * a.w;
        float r4 = b.x * b.x, r5 = b.y * b.y, r6 = b.z * b.z, r7 = b.w * b.w;
        for (int i = 1; i < 16; ++i) {
            a = p[2 * i]; b = p[2 * i + 1];
            r0 += a.x * a.x; r1 += a.y * a.y; r2 += a.z * a.z; r3 += a.w * a.w;
            r4 += b.x * b.x; r5 += b.y * b.y; r6 += b.z * b.z; r7 += b.w * b.w;
        }
        float blk = ((r0 + r1) + (r2 + r3)) + ((r4 + r5) + (r6 + r7));
        s = (h == 0) ? blk : (s + blk);
    }
    out[row] = s;
}

// ---------------- split fp32 -> (hi, lo) bf16 ----------------
__global__ void split_kernel(const float* __restrict__ x,
                             unsigned short* __restrict__ hi,
                             unsigned short* __restrict__ lo, int n4) {
    int i = blockIdx.x * 256 + threadIdx.x;
    if (i >= n4) return;
    float4 v = ((const float4*)x)[i];
    ushort4 h, l;
    h.x = f2bf(v.x); l.x = f2bf(v.x - bf2f(h.x));
    h.y = f2bf(v.y); l.y = f2bf(v.y - bf2f(h.y));
    h.z = f2bf(v.z); l.z = f2bf(v.z - bf2f(h.z));
    h.w = f2bf(v.w); l.w = f2bf(v.w - bf2f(h.w));
    ((ushort4*)hi)[i] = h;
    ((ushort4*)lo)[i] = l;
}

// ---------------- MFMA score GEMM: S = -2*(AhBh^T + AhBl^T + AlBh^T) + ne ---
// 128x128 tile, BK=32, 256 thr = 4 waves; each wave: 32 rows x 128 cols
// (2x8 tiles of 16x16x32). Per-token top-2 + argmin written per code-block.
__global__ __launch_bounds__(256, 2) void mfma_score_kernel(
    const unsigned short* __restrict__ Ah, const unsigned short* __restrict__ Al,
    const unsigned short* __restrict__ Bh, const unsigned short* __restrict__ Bl,
    const float* __restrict__ ne,
    float* __restrict__ p1, float* __restrict__ p2, float* __restrict__ pi) {

    __shared__ unsigned short Asl[128 * 32];
    __shared__ unsigned short Bsl[128 * 32];

    const int tid  = threadIdx.x;
    const int wm   = tid >> 6;          // wave id: rows wm*32..wm*32+31
    const int lane = tid & 63;
    const int L    = lane & 15;
    const int q    = lane >> 4;         // k-quad (8 bf16 each)
    const int m0   = blockIdx.x * 128;
    const int nb   = blockIdx.y;
    const int n0   = nb * 128;

    f32x4 acc[2][8] = {};

    const short8* A8 = (const short8*)Asl;
    const short8* B8 = (const short8*)Bsl;

    for (int ph = 0; ph < 3; ++ph) {
        const unsigned short* PA = (ph == 2) ? Al : Ah;
        const unsigned short* PB = (ph == 1) ? Bl : Bh;
        for (int kt = 0; kt < 8; ++kt) {
            const int k0 = kt * 32;
            __syncthreads();            // previous tile consumed
            #pragma unroll
            for (int r = 0; r < 2; ++r) {
                int u   = tid + 256 * r;
                int row = u >> 2;       // 0..127
                int p   = u & 3;        // 16B chunk slot within row
                int ch  = p ^ ((row >> 1) & 3);   // XOR swizzle
                gl2lds16(PA + (size_t)(m0 + row) * HIDDEN + k0 + ch * 8, &Asl[u * 8]);
                gl2lds16(PB + (size_t)(n0 + row) * HIDDEN + k0 + ch * 8, &Bsl[u * 8]);
            }
            __syncthreads();            // drains vmcnt -> LDS ready

            short8 a[2], b[8];
            #pragma unroll
            for (int tm = 0; tm < 2; ++tm) {
                int m = wm * 32 + tm * 16 + L;
                a[tm] = A8[m * 4 + (q ^ ((m >> 1) & 3))];
            }
            #pragma unroll
            for (int tn = 0; tn < 8; ++tn) {
                int n = tn * 16 + L;
                b[tn] = B8[n * 4 + (q ^ ((n >> 1) & 3))];
            }
            #pragma unroll
            for (int tm = 0; tm < 2; ++tm)
                #pragma unroll
                for (int tn = 0; tn < 8; ++tn)
                    acc[tm][tn] = __builtin_amdgcn_mfma_f32_16x16x32_bf16(
                        a[tm], b[tn], acc[tm][tn], 0, 0, 0);
        }
    }

    // epilogue: s = ne[n] - 2*dot; per-row top-2 across this block's 128 codes
    float nev[8];
    #pragma unroll
    for (int tn = 0; tn < 8; ++tn) nev[tn] = ne[n0 + tn * 16 + L];

    #pragma unroll
    for (int tm = 0; tm < 2; ++tm) {
        #pragma unroll
        for (int reg = 0; reg < 4; ++reg) {
            float m1 = 3.4e38f, m2 = 3.4e38f;
            int bi = 0;
            #pragma unroll
            for (int tn = 0; tn < 8; ++tn) {
                float s = nev[tn] - 2.0f * acc[tm][tn][reg];
                int code = n0 + tn * 16 + L;
                if (s < m1)      { m2 = m1; m1 = s; bi = code; }
                else if (s < m2) { m2 = s; }
            }
            #pragma unroll
            for (int off = 1; off < 16; off <<= 1) {
                float o1 = __shfl_xor(m1, off, 64);
                float o2 = __shfl_xor(m2, off, 64);
                int   oi = __shfl_xor(bi, off, 64);
                if (o1 < m1 || (o1 == m1 && oi < bi)) {
                    m2 = fminf(m1, o2); m1 = o1; bi = oi;
                } else {
                    m2 = fminf(m2, o1);
                }
            }
            if (L == 0) {
                size_t mrow = (size_t)m0 + wm * 32 + tm * 16 + q * 4 + reg;
                p1[(size_t)nb * N_TOK + mrow] = m1;
                p2[(size_t)nb * N_TOK + mrow] = m2;
                pi[(size_t)nb * N_TOK + mrow] = (float)bi;
            }
        }
    }
}

// ---------------- combine per-block partials -> winner + ambiguity flag -----
__global__ void combine_kernel(const float* __restrict__ p1, const float* __restrict__ p2,
                               const float* __restrict__ pi, float* __restrict__ idxf,
                               int* __restrict__ flags) {
    int t = blockIdx.x * 256 + threadIdx.x;
    float m1 = 3.4e38f, m2 = 3.4e38f, bi = 0.0f;
    for (int nb = 0; nb < NBLK; ++nb) {       // ascending nb => ascending codes
        float o1 = p1[(size_t)nb * N_TOK + t];
        float o2 = p2[(size_t)nb * N_TOK + t];
        float oi = pi[(size_t)nb * N_TOK + t];
        if (o1 < m1) { m2 = fminf(m1, o2); m1 = o1; bi = oi; }
        else         { m2 = fminf(m2, o1); }
    }
    idxf[t]  = bi;
    flags[t] = (m2 - m1 < MARGIN) ? 1 : 0;
}

// ---------------- rescue: bit-exact np rescan for ambiguous tokens ----------
__global__ __launch_bounds__(256) void rescue_kernel(
    const float* __restrict__ z, const float* __restrict__ emb,
    const float* __restrict__ ne, const float* __restrict__ zn,
    const int* __restrict__ flags, float* __restrict__ idxf) {
#pragma clang fp contract(off)
    const int t = blockIdx.x;
    if (flags[t] == 0) return;

    __shared__ float zs[HIDDEN];
    if (threadIdx.x < 64)
        ((float4*)zs)[threadIdx.x] = ((const float4*)(z + (size_t)t * HIDDEN))[threadIdx.x];
    __syncthreads();

    const float znt = zn[t];
    float best = 3.4e38f;
    int   bi   = 0x7fffffff;
    for (int c = threadIdx.x; c < K_CODES; c += 256) {
        const float4* e4 = (const float4*)(emb + (size_t)c * HIDDEN);
        float acc = 0.0f;
        for (int k4 = 0; k4 < 64; ++k4) {     // ascending-k single-acc FMA chain
            float4 ev = e4[k4];
            acc = __builtin_fmaf(ev.x, zs[k4 * 4 + 0], acc);
            acc = __builtin_fmaf(ev.y, zs[k4 * 4 + 1], acc);
            acc = __builtin_fmaf(ev.z, zs[k4 * 4 + 2], acc);
            acc = __builtin_fmaf(ev.w, zs[k4 * 4 + 3], acc);
        }
        float t1 = znt - 2.0f * acc;          // np rounding order (R2-proven)
        float s  = t1 + ne[c];
        if (s < best) { best = s; bi = c; }
    }

    __shared__ float sv[256];
    __shared__ int   si[256];
    sv[threadIdx.x] = best; si[threadIdx.x] = bi;
    __syncthreads();
    for (int off = 128; off; off >>= 1) {
        if (threadIdx.x < off) {
            float ov = sv[threadIdx.x + off];
            int   oi = si[threadIdx.x + off];
            if (ov < sv[threadIdx.x] || (ov == sv[threadIdx.x] && oi < si[threadIdx.x])) {
                sv[threadIdx.x] = ov; si[threadIdx.x] = oi;
            }
        }
        __syncthreads();
    }
    if (threadIdx.x == 0) idxf[t] = (float)si[0];
}

// ---------------- gather + straight-through + loss (R2-proven) --------------
__global__ void epilogue_kernel(const float* __restrict__ z, const float* __restrict__ emb,
                                const float* __restrict__ idxf, float* __restrict__ zst,
                                float* __restrict__ loss_accum) {
    int t4    = blockIdx.x * 256 + threadIdx.x;
    int token = t4 >> 6;
    int k4    = t4 & 63;
    int idx   = (int)idxf[token];

    float4 zv = ((const float4*)z)[t4];
    float4 ev = ((const float4*)emb)[(size_t)idx * 64 + k4];

    float dx = ev.x - zv.x, dy = ev.y - zv.y, dz = ev.z - zv.z, dw = ev.w - zv.w;
    float4 o = { zv.x + dx, zv.y + dy, zv.z + dz, zv.w + dw };
    ((float4*)zst)[t4] = o;

    float p = dx * dx + dy * dy + dz * dz + dw * dw;
    #pragma unroll
    for (int off = 32; off; off >>= 1) p += __shfl_down(p, off, 64);

    __shared__ float wsum[4];
    int lane = threadIdx.x & 63, w = threadIdx.x >> 6;
    if (lane == 0) wsum[w] = p;
    __syncthreads();
    if (threadIdx.x == 0)
        atomicAdd(loss_accum, wsum[0] + wsum[1] + wsum[2] + wsum[3]);
}

__global__ void finalize_kernel(const float* __restrict__ loss_accum,
                                float* __restrict__ out_losses) {
    float m = loss_accum[0] * (1.0f / (float)ZST_ELEMS);
    out_losses[0] = m;
    out_losses[1] = m;
}

// ---------------- launch ----------------
extern "C" void kernel_launch(void* const* d_in, const int* in_sizes, int n_in,
                              void* d_out, int out_size, void* d_ws, size_t ws_size,
                              hipStream_t stream) {
    const float* z   = (const float*)d_in[0];   // [8,4096,256]
    const float* emb = (const float*)d_in[1];   // [8192,256]

    float* out    = (float*)d_out;
    float* zst    = out;                        // 8388608
    float* idxf   = out + ZST_ELEMS;            // 32768
    float* losses = out + ZST_ELEMS + N_TOK;    // 2

    // workspace layout (bytes): bf16 splits + partials + norms + flags
    char* w = (char*)d_ws;
    unsigned short* Ah = (unsigned short*)w;            w += (size_t)N_TOK  * HIDDEN * 2;
    unsigned short* Al = (unsigned short*)w;            w += (size_t)N_TOK  * HIDDEN * 2;
    unsigned short* Bh = (unsigned short*)w;            w += (size_t)K_CODES * HIDDEN * 2;
    unsigned short* Bl = (unsigned short*)w;            w += (size_t)K_CODES * HIDDEN * 2;
    float* p1 = (float*)w;                              w += (size_t)NBLK * N_TOK * 4;
    float* p2 = (float*)w;                              w += (size_t)NBLK * N_TOK * 4;
    float* pi = (float*)w;                              w += (size_t)NBLK * N_TOK * 4;
    float* ne = (float*)w;                              w += K_CODES * 4;
    float* zn = (float*)w;                              w += N_TOK * 4;
    int*   flags = (int*)w;                             w += N_TOK * 4;
    float* loss_accum = (float*)w;

    hipMemsetAsync(loss_accum, 0, sizeof(float), stream);
    np_norms_kernel<<<K_CODES / 256, 256, 0, stream>>>(emb, ne, K_CODES);
    np_norms_kernel<<<N_TOK / 256, 256, 0, stream>>>(z, zn, N_TOK);
    split_kernel<<<(ZST_ELEMS / 4) / 256, 256, 0, stream>>>(z, Ah, Al, ZST_ELEMS / 4);
    split_kernel<<<(K_CODES * HIDDEN / 4) / 256, 256, 0, stream>>>(emb, Bh, Bl,
                                                                   K_CODES * HIDDEN / 4);
    dim3 gg(N_TOK / 128, NBLK);
    mfma_score_kernel<<<gg, 256, 0, stream>>>(Ah, Al, Bh, Bl, ne, p1, p2, pi);
    combine_kernel<<<N_TOK / 256, 256, 0, stream>>>(p1, p2, pi, idxf, flags);
    rescue_kernel<<<N_TOK, 256, 0, stream>>>(z, emb, ne, zn, flags, idxf);
    epilogue_kernel<<<(ZST_ELEMS / 4) / 256, 256, 0, stream>>>(z, emb, idxf, zst, loss_accum);
    finalize_kernel<<<1, 1, 0, stream>>>(loss_accum, losses);
}

// Round 5
// 828.262 us; speedup vs baseline: 2.8060x; 1.9390x over previous
//
#include <hip/hip_runtime.h>

#define HIDDEN 256
#define K_CODES 8192
#define N_TOK 32768           // 8 * 4096
#define ZST_ELEMS 8388608     // 8*4096*256
#define NBLK 64               // code-dim blocks in MFMA gemm (8192/128)
#define MARGIN 1.0e-3f        // >> worst-case split-bf16 score error ~3e-5
#define WL_CAP 65536

using short8 = __attribute__((ext_vector_type(8))) short;   // 8 bf16 (4 VGPRs)
using f32x4  = __attribute__((ext_vector_type(4))) float;   // MFMA C/D frag

// ---------- deterministic RNE fp32->bf16 ----------
__device__ __forceinline__ unsigned short f2bf(float f) {
    unsigned int u = __float_as_uint(f);
    return (unsigned short)((u + 0x7fffu + ((u >> 16) & 1u)) >> 16);
}
__device__ __forceinline__ float bf2f(unsigned short h) {
    return __uint_as_float(((unsigned int)h) << 16);
}

__device__ __forceinline__ void gl2lds16(const void* g, void* l) {
    __builtin_amdgcn_global_load_lds(
        (const __attribute__((address_space(1))) unsigned int*)g,
        (__attribute__((address_space(3))) unsigned int*)l, 16, 0, 0);
}

// orderable key: monotone float->uint, packed with code for lowest-idx tie-break
__device__ __forceinline__ unsigned long long score_key(float s, int code) {
    unsigned int u = __float_as_uint(s);
    u = (u & 0x80000000u) ? ~u : (u | 0x80000000u);
    return (((unsigned long long)u) << 32) | (unsigned int)code;
}

// ---------------- numpy-pairwise row sum-of-squares (R2-proven exact) -------
__global__ void np_norms_kernel(const float* __restrict__ x, float* __restrict__ out,
                                int nrows) {
#pragma clang fp contract(off)
    int row = blockIdx.x * 256 + threadIdx.x;
    if (row >= nrows) return;
    const float4* q = (const float4*)(x + (size_t)row * HIDDEN);
    float s = 0.0f;
    for (int h = 0; h < 2; ++h) {
        const float4* p = q + h * 32;
        float4 a = p[0], b = p[1];
        float r0 = a.x * a.x, r1 = a.y * a.y, r2 = a.z * a.z, r3 = a.w * a.w;
        float r4 = b.x * b.x, r5 = b.y * b.y, r6 = b.z * b.z, r7 = b.w * b.w;
        for (int i = 1; i < 16; ++i) {
            a = p[2 * i]; b = p[2 * i + 1];
            r0 += a.x * a.x; r1 += a.y * a.y; r2 += a.z * a.z; r3 += a.w * a.w;
            r4 += b.x * b.x; r5 += b.y * b.y; r6 += b.z * b.z; r7 += b.w * b.w;
        }
        float blk = ((r0 + r1) + (r2 + r3)) + ((r4 + r5) + (r6 + r7));
        s = (h == 0) ? blk : (s + blk);
    }
    out[row] = s;
}

// ---------------- split fp32 -> (hi, lo) bf16 ----------------
__global__ void split_kernel(const float* __restrict__ x,
                             unsigned short* __restrict__ hi,
                             unsigned short* __restrict__ lo, int n4) {
    int i = blockIdx.x * 256 + threadIdx.x;
    if (i >= n4) return;
    float4 v = ((const float4*)x)[i];
    ushort4 h, l;
    h.x = f2bf(v.x); l.x = f2bf(v.x - bf2f(h.x));
    h.y = f2bf(v.y); l.y = f2bf(v.y - bf2f(h.y));
    h.z = f2bf(v.z); l.z = f2bf(v.z - bf2f(h.z));
    h.w = f2bf(v.w); l.w = f2bf(v.w - bf2f(h.w));
    ((ushort4*)hi)[i] = h;
    ((ushort4*)lo)[i] = l;
}

// ---------------- MFMA score GEMM (R3-proven) ----------------
__global__ __launch_bounds__(256, 2) void mfma_score_kernel(
    const unsigned short* __restrict__ Ah, const unsigned short* __restrict__ Al,
    const unsigned short* __restrict__ Bh, const unsigned short* __restrict__ Bl,
    const float* __restrict__ ne,
    float* __restrict__ p1, float* __restrict__ p2, unsigned short* __restrict__ piu) {

    __shared__ unsigned short Asl[128 * 32];
    __shared__ unsigned short Bsl[128 * 32];

    const int tid  = threadIdx.x;
    const int wm   = tid >> 6;
    const int lane = tid & 63;
    const int L    = lane & 15;
    const int q    = lane >> 4;
    const int m0   = blockIdx.x * 128;
    const int nb   = blockIdx.y;
    const int n0   = nb * 128;

    f32x4 acc[2][8] = {};

    const short8* A8 = (const short8*)Asl;
    const short8* B8 = (const short8*)Bsl;

    for (int ph = 0; ph < 3; ++ph) {
        const unsigned short* PA = (ph == 2) ? Al : Ah;
        const unsigned short* PB = (ph == 1) ? Bl : Bh;
        for (int kt = 0; kt < 8; ++kt) {
            const int k0 = kt * 32;
            __syncthreads();
            #pragma unroll
            for (int r = 0; r < 2; ++r) {
                int u   = tid + 256 * r;
                int row = u >> 2;
                int p   = u & 3;
                int ch  = p ^ ((row >> 1) & 3);
                gl2lds16(PA + (size_t)(m0 + row) * HIDDEN + k0 + ch * 8, &Asl[u * 8]);
                gl2lds16(PB + (size_t)(n0 + row) * HIDDEN + k0 + ch * 8, &Bsl[u * 8]);
            }
            __syncthreads();

            short8 a[2], b[8];
            #pragma unroll
            for (int tm = 0; tm < 2; ++tm) {
                int m = wm * 32 + tm * 16 + L;
                a[tm] = A8[m * 4 + (q ^ ((m >> 1) & 3))];
            }
            #pragma unroll
            for (int tn = 0; tn < 8; ++tn) {
                int n = tn * 16 + L;
                b[tn] = B8[n * 4 + (q ^ ((n >> 1) & 3))];
            }
            #pragma unroll
            for (int tm = 0; tm < 2; ++tm)
                #pragma unroll
                for (int tn = 0; tn < 8; ++tn)
                    acc[tm][tn] = __builtin_amdgcn_mfma_f32_16x16x32_bf16(
                        a[tm], b[tn], acc[tm][tn], 0, 0, 0);
        }
    }

    float nev[8];
    #pragma unroll
    for (int tn = 0; tn < 8; ++tn) nev[tn] = ne[n0 + tn * 16 + L];

    #pragma unroll
    for (int tm = 0; tm < 2; ++tm) {
        #pragma unroll
        for (int reg = 0; reg < 4; ++reg) {
            float m1 = 3.4e38f, m2 = 3.4e38f;
            int bi = 0;
            #pragma unroll
            for (int tn = 0; tn < 8; ++tn) {
                float s = nev[tn] - 2.0f * acc[tm][tn][reg];
                int lo = tn * 16 + L;               // local code 0..127
                if (s < m1)      { m2 = m1; m1 = s; bi = lo; }
                else if (s < m2) { m2 = s; }
            }
            #pragma unroll
            for (int off = 1; off < 16; off <<= 1) {
                float o1 = __shfl_xor(m1, off, 64);
                float o2 = __shfl_xor(m2, off, 64);
                int   oi = __shfl_xor(bi, off, 64);
                if (o1 < m1 || (o1 == m1 && oi < bi)) {
                    m2 = fminf(m1, o2); m1 = o1; bi = oi;
                } else {
                    m2 = fminf(m2, o1);
                }
            }
            if (L == 0) {
                size_t mrow = (size_t)m0 + wm * 32 + tm * 16 + q * 4 + reg;
                p1[(size_t)nb * N_TOK + mrow]  = m1;
                p2[(size_t)nb * N_TOK + mrow]  = m2;
                piu[(size_t)nb * N_TOK + mrow] = (unsigned short)bi;
            }
        }
    }
}

// ------- combine partials -> winner + ambiguity flag + pruned worklist ------
__global__ void combine_kernel(const float* __restrict__ p1, const float* __restrict__ p2,
                               const unsigned short* __restrict__ piu,
                               float* __restrict__ idxf, int* __restrict__ flags,
                               unsigned long long* __restrict__ slots,
                               int* __restrict__ wl, unsigned int* __restrict__ wcount) {
    int t = blockIdx.x * 256 + threadIdx.x;
    float m1 = 3.4e38f, m2 = 3.4e38f;
    int bi = 0;
    for (int nb = 0; nb < NBLK; ++nb) {       // ascending nb => ascending codes
        float o1 = p1[(size_t)nb * N_TOK + t];
        float o2 = p2[(size_t)nb * N_TOK + t];
        if (o1 < m1) {
            m2 = fminf(m1, o2); m1 = o1;
            bi = nb * 128 + (int)piu[(size_t)nb * N_TOK + t];
        } else {
            m2 = fminf(m2, o1);
        }
    }
    idxf[t]  = (float)bi;
    slots[t] = ~0ULL;
    bool amb = (m2 - m1 < MARGIN);
    flags[t] = amb ? 1 : 0;
    if (amb) {
        // only chunks whose approx min is within margin can hold the np winner
        for (int nb = 0; nb < NBLK; ++nb) {
            if (p1[(size_t)nb * N_TOK + t] <= m1 + MARGIN) {
                unsigned int pos = atomicAdd(wcount, 1u);
                if (pos < WL_CAP) wl[pos] = (t << 6) | nb;
            }
        }
    }
}

// ---------------- rescue: np-exact rescan of pruned (token,chunk) items -----
__global__ __launch_bounds__(128) void rescue_scan(
    const float* __restrict__ z, const float* __restrict__ emb,
    const float* __restrict__ ne, const float* __restrict__ zn,
    const int* __restrict__ wl, const unsigned int* __restrict__ wcount,
    unsigned long long* __restrict__ slots) {
#pragma clang fp contract(off)
    __shared__ float zs[HIDDEN];
    __shared__ unsigned long long red[128];

    int nit = (int)*wcount;
    if (nit > WL_CAP) nit = WL_CAP;

    for (int item = blockIdx.x; item < nit; item += gridDim.x) {
        int w  = wl[item];
        int t  = w >> 6;
        int nb = w & 63;
        __syncthreads();                       // zs/red from previous item consumed
        if (threadIdx.x < 64)
            ((float4*)zs)[threadIdx.x] =
                ((const float4*)(z + (size_t)t * HIDDEN))[threadIdx.x];
        __syncthreads();

        int c = nb * 128 + threadIdx.x;        // one code per thread
        const float4* e4 = (const float4*)(emb + (size_t)c * HIDDEN);
        float acc = 0.0f;
        #pragma unroll 8
        for (int k4 = 0; k4 < 64; ++k4) {      // ascending-k single-acc FMA chain
            float4 ev = e4[k4];
            acc = __builtin_fmaf(ev.x, zs[k4 * 4 + 0], acc);
            acc = __builtin_fmaf(ev.y, zs[k4 * 4 + 1], acc);
            acc = __builtin_fmaf(ev.z, zs[k4 * 4 + 2], acc);
            acc = __builtin_fmaf(ev.w, zs[k4 * 4 + 3], acc);
        }
        float t1 = zn[t] - 2.0f * acc;         // np rounding order (R2-proven)
        float s  = t1 + ne[c];

        red[threadIdx.x] = score_key(s, c);
        __syncthreads();
        for (int off = 64; off; off >>= 1) {
            if (threadIdx.x < off) {
                unsigned long long o = red[threadIdx.x + off];
                if (o < red[threadIdx.x]) red[threadIdx.x] = o;
            }
            __syncthreads();
        }
        if (threadIdx.x == 0) atomicMin(&slots[t], red[0]);
    }
}

__global__ void rescue_fin(const int* __restrict__ flags,
                           const unsigned long long* __restrict__ slots,
                           float* __restrict__ idxf) {
    int t = blockIdx.x * 256 + threadIdx.x;
    if (flags[t]) idxf[t] = (float)(unsigned int)(slots[t] & 0xFFFFFFFFULL);
}

// ---------------- gather + straight-through + loss (R2-proven) --------------
__global__ void epilogue_kernel(const float* __restrict__ z, const float* __restrict__ emb,
                                const float* __restrict__ idxf, float* __restrict__ zst,
                                float* __restrict__ loss_accum) {
    int t4    = blockIdx.x * 256 + threadIdx.x;
    int token = t4 >> 6;
    int k4    = t4 & 63;
    int idx   = (int)idxf[token];

    float4 zv = ((const float4*)z)[t4];
    float4 ev = ((const float4*)emb)[(size_t)idx * 64 + k4];

    float dx = ev.x - zv.x, dy = ev.y - zv.y, dz = ev.z - zv.z, dw = ev.w - zv.w;
    float4 o = { zv.x + dx, zv.y + dy, zv.z + dz, zv.w + dw };
    ((float4*)zst)[t4] = o;

    float p = dx * dx + dy * dy + dz * dz + dw * dw;
    #pragma unroll
    for (int off = 32; off; off >>= 1) p += __shfl_down(p, off, 64);

    __shared__ float wsum[4];
    int lane = threadIdx.x & 63, w = threadIdx.x >> 6;
    if (lane == 0) wsum[w] = p;
    __syncthreads();
    if (threadIdx.x == 0)
        atomicAdd(loss_accum, wsum[0] + wsum[1] + wsum[2] + wsum[3]);
}

__global__ void finalize_kernel(const float* __restrict__ loss_accum,
                                float* __restrict__ out_losses) {
    float m = loss_accum[0] * (1.0f / (float)ZST_ELEMS);
    out_losses[0] = m;
    out_losses[1] = m;
}

// ---------------- launch ----------------
extern "C" void kernel_launch(void* const* d_in, const int* in_sizes, int n_in,
                              void* d_out, int out_size, void* d_ws, size_t ws_size,
                              hipStream_t stream) {
    const float* z   = (const float*)d_in[0];   // [8,4096,256]
    const float* emb = (const float*)d_in[1];   // [8192,256]

    float* out    = (float*)d_out;
    float* zst    = out;                        // 8388608
    float* idxf   = out + ZST_ELEMS;            // 32768
    float* losses = out + ZST_ELEMS + N_TOK;    // 2

    char* w = (char*)d_ws;
    unsigned short* Ah = (unsigned short*)w;    w += (size_t)N_TOK  * HIDDEN * 2;
    unsigned short* Al = (unsigned short*)w;    w += (size_t)N_TOK  * HIDDEN * 2;
    unsigned short* Bh = (unsigned short*)w;    w += (size_t)K_CODES * HIDDEN * 2;
    unsigned short* Bl = (unsigned short*)w;    w += (size_t)K_CODES * HIDDEN * 2;
    float* p1 = (float*)w;                      w += (size_t)NBLK * N_TOK * 4;
    float* p2 = (float*)w;                      w += (size_t)NBLK * N_TOK * 4;
    unsigned short* piu = (unsigned short*)w;   w += (size_t)NBLK * N_TOK * 2;
    float* ne = (float*)w;                      w += K_CODES * 4;
    float* zn = (float*)w;                      w += N_TOK * 4;
    int*   flags = (int*)w;                     w += N_TOK * 4;
    unsigned long long* slots = (unsigned long long*)w;  w += N_TOK * 8;
    int*   wl = (int*)w;                        w += WL_CAP * 4;
    float* loss_accum = (float*)w;              w += 4;
    unsigned int* wcount = (unsigned int*)w;    // adjacent to loss_accum

    hipMemsetAsync(loss_accum, 0, 8, stream);   // zero loss + worklist counter
    np_norms_kernel<<<K_CODES / 256, 256, 0, stream>>>(emb, ne, K_CODES);
    np_norms_kernel<<<N_TOK / 256, 256, 0, stream>>>(z, zn, N_TOK);
    split_kernel<<<(ZST_ELEMS / 4) / 256, 256, 0, stream>>>(z, Ah, Al, ZST_ELEMS / 4);
    split_kernel<<<(K_CODES * HIDDEN / 4) / 256, 256, 0, stream>>>(emb, Bh, Bl,
                                                                   K_CODES * HIDDEN / 4);
    dim3 gg(N_TOK / 128, NBLK);
    mfma_score_kernel<<<gg, 256, 0, stream>>>(Ah, Al, Bh, Bl, ne, p1, p2, piu);
    combine_kernel<<<N_TOK / 256, 256, 0, stream>>>(p1, p2, piu, idxf, flags,
                                                    slots, wl, wcount);
    rescue_scan<<<1024, 128, 0, stream>>>(z, emb, ne, zn, wl, wcount, slots);
    rescue_fin<<<N_TOK / 256, 256, 0, stream>>>(flags, slots, idxf);
    epilogue_kernel<<<(ZST_ELEMS / 4) / 256, 256, 0, stream>>>(z, emb, idxf, zst, loss_accum);
    finalize_kernel<<<1, 1, 0, stream>>>(loss_accum, losses);
}

// Round 6
// 693.867 us; speedup vs baseline: 3.3495x; 1.1937x over previous
//
#include <hip/hip_runtime.h>

#define HIDDEN 256
#define K_CODES 8192
#define N_TOK 32768           // 8 * 4096
#define ZST_ELEMS 8388608     // 8*4096*256
#define NBLK 64               // code-dim blocks in MFMA gemm (8192/128)
#define MARGIN 1.0e-3f        // >> worst-case split-bf16 score error ~1e-4
#define WL_CAP 65536

using short8 = __attribute__((ext_vector_type(8))) short;   // 8 bf16 (4 VGPRs)
using f32x4  = __attribute__((ext_vector_type(4))) float;   // MFMA C/D frag

// ---------- deterministic RNE fp32->bf16 ----------
__device__ __forceinline__ unsigned short f2bf(float f) {
    unsigned int u = __float_as_uint(f);
    return (unsigned short)((u + 0x7fffu + ((u >> 16) & 1u)) >> 16);
}
__device__ __forceinline__ float bf2f(unsigned short h) {
    return __uint_as_float(((unsigned int)h) << 16);
}

__device__ __forceinline__ void gl2lds16(const void* g, void* l) {
    __builtin_amdgcn_global_load_lds(
        (const __attribute__((address_space(1))) unsigned int*)g,
        (__attribute__((address_space(3))) unsigned int*)l, 16, 0, 0);
}

// orderable key: monotone float->uint, packed with code for lowest-idx tie-break
__device__ __forceinline__ unsigned long long score_key(float s, int code) {
    unsigned int u = __float_as_uint(s);
    u = (u & 0x80000000u) ? ~u : (u | 0x80000000u);
    return (((unsigned long long)u) << 32) | (unsigned int)code;
}

// ---------------- numpy-pairwise row sum-of-squares (R2-proven exact) -------
__global__ void np_norms_kernel(const float* __restrict__ x, float* __restrict__ out,
                                int nrows) {
#pragma clang fp contract(off)
    int row = blockIdx.x * 256 + threadIdx.x;
    if (row >= nrows) return;
    const float4* q = (const float4*)(x + (size_t)row * HIDDEN);
    float s = 0.0f;
    for (int h = 0; h < 2; ++h) {
        const float4* p = q + h * 32;
        float4 a = p[0], b = p[1];
        float r0 = a.x * a.x, r1 = a.y * a.y, r2 = a.z * a.z, r3 = a.w * a.w;
        float r4 = b.x * b.x, r5 = b.y * b.y, r6 = b.z * b.z, r7 = b.w * b.w;
        for (int i = 1; i < 16; ++i) {
            a = p[2 * i]; b = p[2 * i + 1];
            r0 += a.x * a.x; r1 += a.y * a.y; r2 += a.z * a.z; r3 += a.w * a.w;
            r4 += b.x * b.x; r5 += b.y * b.y; r6 += b.z * b.z; r7 += b.w * b.w;
        }
        float blk = ((r0 + r1) + (r2 + r3)) + ((r4 + r5) + (r6 + r7));
        s = (h == 0) ? blk : (s + blk);
    }
    out[row] = s;
}

// ---------------- split fp32 -> (hi, lo) bf16 ----------------
__global__ void split_kernel(const float* __restrict__ x,
                             unsigned short* __restrict__ hi,
                             unsigned short* __restrict__ lo, int n4) {
    int i = blockIdx.x * 256 + threadIdx.x;
    if (i >= n4) return;
    float4 v = ((const float4*)x)[i];
    ushort4 h, l;
    h.x = f2bf(v.x); l.x = f2bf(v.x - bf2f(h.x));
    h.y = f2bf(v.y); l.y = f2bf(v.y - bf2f(h.y));
    h.z = f2bf(v.z); l.z = f2bf(v.z - bf2f(h.z));
    h.w = f2bf(v.w); l.w = f2bf(v.w - bf2f(h.w));
    ((ushort4*)hi)[i] = h;
    ((ushort4*)lo)[i] = l;
}

// ------- MFMA score GEMM: fused 3-product K-loop (Ah·Bh + Al·Bh + Ah·Bl) ----
// 128x128 tile, BK=32; per kt stage all 4 tiles (32 KB LDS) once, issue 48
// MFMA against 20 ds_read_b128 (balanced), 8 barrier-pairs total (was 24).
__global__ __launch_bounds__(256, 2) void mfma_score_kernel(
    const unsigned short* __restrict__ Ah, const unsigned short* __restrict__ Al,
    const unsigned short* __restrict__ Bh, const unsigned short* __restrict__ Bl,
    const float* __restrict__ ne,
    float* __restrict__ p1, float* __restrict__ p2, unsigned short* __restrict__ piu) {

    __shared__ unsigned short Ahs[128 * 32];
    __shared__ unsigned short Als[128 * 32];
    __shared__ unsigned short Bhs[128 * 32];
    __shared__ unsigned short Bls[128 * 32];

    const int tid  = threadIdx.x;
    const int wm   = tid >> 6;
    const int lane = tid & 63;
    const int L    = lane & 15;
    const int q    = lane >> 4;
    const int m0   = blockIdx.x * 128;
    const int nb   = blockIdx.y;
    const int n0   = nb * 128;

    f32x4 acc[2][8] = {};

    const short8* A8h = (const short8*)Ahs;
    const short8* A8l = (const short8*)Als;
    const short8* B8h = (const short8*)Bhs;
    const short8* B8l = (const short8*)Bls;

    for (int kt = 0; kt < 8; ++kt) {
        const int k0 = kt * 32;
        __syncthreads();                     // previous tiles consumed
        #pragma unroll
        for (int r = 0; r < 2; ++r) {
            int u   = tid + 256 * r;
            int row = u >> 2;
            int p   = u & 3;
            int ch  = p ^ ((row >> 1) & 3);  // XOR swizzle
            size_t ga = (size_t)(m0 + row) * HIDDEN + k0 + ch * 8;
            size_t gb = (size_t)(n0 + row) * HIDDEN + k0 + ch * 8;
            gl2lds16(Ah + ga, &Ahs[u * 8]);
            gl2lds16(Al + ga, &Als[u * 8]);
            gl2lds16(Bh + gb, &Bhs[u * 8]);
            gl2lds16(Bl + gb, &Bls[u * 8]);
        }
        __syncthreads();                     // drains vmcnt -> LDS ready

        short8 ah[2], al[2];
        #pragma unroll
        for (int tm = 0; tm < 2; ++tm) {
            int m  = wm * 32 + tm * 16 + L;
            int fi = m * 4 + (q ^ ((m >> 1) & 3));
            ah[tm] = A8h[fi];
            al[tm] = A8l[fi];
        }
        #pragma unroll
        for (int tn = 0; tn < 8; ++tn) {
            int n  = tn * 16 + L;
            int fi = n * 4 + (q ^ ((n >> 1) & 3));
            short8 bh = B8h[fi];
            short8 bl = B8l[fi];
            #pragma unroll
            for (int tm = 0; tm < 2; ++tm) {
                acc[tm][tn] = __builtin_amdgcn_mfma_f32_16x16x32_bf16(
                    ah[tm], bh, acc[tm][tn], 0, 0, 0);
                acc[tm][tn] = __builtin_amdgcn_mfma_f32_16x16x32_bf16(
                    al[tm], bh, acc[tm][tn], 0, 0, 0);
                acc[tm][tn] = __builtin_amdgcn_mfma_f32_16x16x32_bf16(
                    ah[tm], bl, acc[tm][tn], 0, 0, 0);
            }
        }
    }

    float nev[8];
    #pragma unroll
    for (int tn = 0; tn < 8; ++tn) nev[tn] = ne[n0 + tn * 16 + L];

    #pragma unroll
    for (int tm = 0; tm < 2; ++tm) {
        #pragma unroll
        for (int reg = 0; reg < 4; ++reg) {
            float m1 = 3.4e38f, m2 = 3.4e38f;
            int bi = 0;
            #pragma unroll
            for (int tn = 0; tn < 8; ++tn) {
                float s = nev[tn] - 2.0f * acc[tm][tn][reg];
                int lo = tn * 16 + L;               // local code 0..127
                if (s < m1)      { m2 = m1; m1 = s; bi = lo; }
                else if (s < m2) { m2 = s; }
            }
            #pragma unroll
            for (int off = 1; off < 16; off <<= 1) {
                float o1 = __shfl_xor(m1, off, 64);
                float o2 = __shfl_xor(m2, off, 64);
                int   oi = __shfl_xor(bi, off, 64);
                if (o1 < m1 || (o1 == m1 && oi < bi)) {
                    m2 = fminf(m1, o2); m1 = o1; bi = oi;
                } else {
                    m2 = fminf(m2, o1);
                }
            }
            if (L == 0) {
                size_t mrow = (size_t)m0 + wm * 32 + tm * 16 + q * 4 + reg;
                p1[(size_t)nb * N_TOK + mrow]  = m1;
                p2[(size_t)nb * N_TOK + mrow]  = m2;
                piu[(size_t)nb * N_TOK + mrow] = (unsigned short)bi;
            }
        }
    }
}

// ------- combine partials -> winner + ambiguity flag + pruned worklist ------
__global__ void combine_kernel(const float* __restrict__ p1, const float* __restrict__ p2,
                               const unsigned short* __restrict__ piu,
                               float* __restrict__ idxf, int* __restrict__ flags,
                               unsigned long long* __restrict__ slots,
                               int* __restrict__ wl, unsigned int* __restrict__ wcount) {
    int t = blockIdx.x * 256 + threadIdx.x;
    float m1 = 3.4e38f, m2 = 3.4e38f;
    int bi = 0;
    for (int nb = 0; nb < NBLK; ++nb) {       // ascending nb => ascending codes
        float o1 = p1[(size_t)nb * N_TOK + t];
        float o2 = p2[(size_t)nb * N_TOK + t];
        if (o1 < m1) {
            m2 = fminf(m1, o2); m1 = o1;
            bi = nb * 128 + (int)piu[(size_t)nb * N_TOK + t];
        } else {
            m2 = fminf(m2, o1);
        }
    }
    idxf[t]  = (float)bi;
    slots[t] = ~0ULL;
    bool amb = (m2 - m1 < MARGIN);
    flags[t] = amb ? 1 : 0;
    if (amb) {
        // only chunks whose approx min is within margin can hold the np winner
        for (int nb = 0; nb < NBLK; ++nb) {
            if (p1[(size_t)nb * N_TOK + t] <= m1 + MARGIN) {
                unsigned int pos = atomicAdd(wcount, 1u);
                if (pos < WL_CAP) wl[pos] = (t << 6) | nb;
            }
        }
    }
}

// ---------------- rescue: np-exact rescan of pruned (token,chunk) items -----
__global__ __launch_bounds__(128) void rescue_scan(
    const float* __restrict__ z, const float* __restrict__ emb,
    const float* __restrict__ ne, const float* __restrict__ zn,
    const int* __restrict__ wl, const unsigned int* __restrict__ wcount,
    unsigned long long* __restrict__ slots) {
#pragma clang fp contract(off)
    __shared__ float zs[HIDDEN];
    __shared__ unsigned long long red[128];

    int nit = (int)*wcount;
    if (nit > WL_CAP) nit = WL_CAP;

    for (int item = blockIdx.x; item < nit; item += gridDim.x) {
        int w  = wl[item];
        int t  = w >> 6;
        int nb = w & 63;
        __syncthreads();                       // zs/red from previous item consumed
        if (threadIdx.x < 64)
            ((float4*)zs)[threadIdx.x] =
                ((const float4*)(z + (size_t)t * HIDDEN))[threadIdx.x];
        __syncthreads();

        int c = nb * 128 + threadIdx.x;        // one code per thread
        const float4* e4 = (const float4*)(emb + (size_t)c * HIDDEN);
        float acc = 0.0f;
        #pragma unroll 8
        for (int k4 = 0; k4 < 64; ++k4) {      // ascending-k single-acc FMA chain
            float4 ev = e4[k4];
            acc = __builtin_fmaf(ev.x, zs[k4 * 4 + 0], acc);
            acc = __builtin_fmaf(ev.y, zs[k4 * 4 + 1], acc);
            acc = __builtin_fmaf(ev.z, zs[k4 * 4 + 2], acc);
            acc = __builtin_fmaf(ev.w, zs[k4 * 4 + 3], acc);
        }
        float t1 = zn[t] - 2.0f * acc;         // np rounding order (R2-proven)
        float s  = t1 + ne[c];

        red[threadIdx.x] = score_key(s, c);
        __syncthreads();
        for (int off = 64; off; off >>= 1) {
            if (threadIdx.x < off) {
                unsigned long long o = red[threadIdx.x + off];
                if (o < red[threadIdx.x]) red[threadIdx.x] = o;
            }
            __syncthreads();
        }
        if (threadIdx.x == 0) atomicMin(&slots[t], red[0]);
    }
}

__global__ void rescue_fin(const int* __restrict__ flags,
                           const unsigned long long* __restrict__ slots,
                           float* __restrict__ idxf) {
    int t = blockIdx.x * 256 + threadIdx.x;
    if (flags[t]) idxf[t] = (float)(unsigned int)(slots[t] & 0xFFFFFFFFULL);
}

// ---------------- gather + straight-through + loss (R2-proven) --------------
__global__ void epilogue_kernel(const float* __restrict__ z, const float* __restrict__ emb,
                                const float* __restrict__ idxf, float* __restrict__ zst,
                                float* __restrict__ loss_accum) {
    int t4    = blockIdx.x * 256 + threadIdx.x;
    int token = t4 >> 6;
    int k4    = t4 & 63;
    int idx   = (int)idxf[token];

    float4 zv = ((const float4*)z)[t4];
    float4 ev = ((const float4*)emb)[(size_t)idx * 64 + k4];

    float dx = ev.x - zv.x, dy = ev.y - zv.y, dz = ev.z - zv.z, dw = ev.w - zv.w;
    float4 o = { zv.x + dx, zv.y + dy, zv.z + dz, zv.w + dw };
    ((float4*)zst)[t4] = o;

    float p = dx * dx + dy * dy + dz * dz + dw * dw;
    #pragma unroll
    for (int off = 32; off; off >>= 1) p += __shfl_down(p, off, 64);

    __shared__ float wsum[4];
    int lane = threadIdx.x & 63, w = threadIdx.x >> 6;
    if (lane == 0) wsum[w] = p;
    __syncthreads();
    if (threadIdx.x == 0)
        atomicAdd(loss_accum, wsum[0] + wsum[1] + wsum[2] + wsum[3]);
}

__global__ void finalize_kernel(const float* __restrict__ loss_accum,
                                float* __restrict__ out_losses) {
    float m = loss_accum[0] * (1.0f / (float)ZST_ELEMS);
    out_losses[0] = m;
    out_losses[1] = m;
}

// ---------------- launch ----------------
extern "C" void kernel_launch(void* const* d_in, const int* in_sizes, int n_in,
                              void* d_out, int out_size, void* d_ws, size_t ws_size,
                              hipStream_t stream) {
    const float* z   = (const float*)d_in[0];   // [8,4096,256]
    const float* emb = (const float*)d_in[1];   // [8192,256]

    float* out    = (float*)d_out;
    float* zst    = out;                        // 8388608
    float* idxf   = out + ZST_ELEMS;            // 32768
    float* losses = out + ZST_ELEMS + N_TOK;    // 2

    char* w = (char*)d_ws;
    unsigned short* Ah = (unsigned short*)w;    w += (size_t)N_TOK  * HIDDEN * 2;
    unsigned short* Al = (unsigned short*)w;    w += (size_t)N_TOK  * HIDDEN * 2;
    unsigned short* Bh = (unsigned short*)w;    w += (size_t)K_CODES * HIDDEN * 2;
    unsigned short* Bl = (unsigned short*)w;    w += (size_t)K_CODES * HIDDEN * 2;
    float* p1 = (float*)w;                      w += (size_t)NBLK * N_TOK * 4;
    float* p2 = (float*)w;                      w += (size_t)NBLK * N_TOK * 4;
    unsigned short* piu = (unsigned short*)w;   w += (size_t)NBLK * N_TOK * 2;
    float* ne = (float*)w;                      w += K_CODES * 4;
    float* zn = (float*)w;                      w += N_TOK * 4;
    int*   flags = (int*)w;                     w += N_TOK * 4;
    unsigned long long* slots = (unsigned long long*)w;  w += N_TOK * 8;
    int*   wl = (int*)w;                        w += WL_CAP * 4;
    float* loss_accum = (float*)w;              w += 4;
    unsigned int* wcount = (unsigned int*)w;    // adjacent to loss_accum

    hipMemsetAsync(loss_accum, 0, 8, stream);   // zero loss + worklist counter
    np_norms_kernel<<<K_CODES / 256, 256, 0, stream>>>(emb, ne, K_CODES);
    np_norms_kernel<<<N_TOK / 256, 256, 0, stream>>>(z, zn, N_TOK);
    split_kernel<<<(ZST_ELEMS / 4) / 256, 256, 0, stream>>>(z, Ah, Al, ZST_ELEMS / 4);
    split_kernel<<<(K_CODES * HIDDEN / 4) / 256, 256, 0, stream>>>(emb, Bh, Bl,
                                                                   K_CODES * HIDDEN / 4);
    dim3 gg(N_TOK / 128, NBLK);
    mfma_score_kernel<<<gg, 256, 0, stream>>>(Ah, Al, Bh, Bl, ne, p1, p2, piu);
    combine_kernel<<<N_TOK / 256, 256, 0, stream>>>(p1, p2, piu, idxf, flags,
                                                    slots, wl, wcount);
    rescue_scan<<<1024, 128, 0, stream>>>(z, emb, ne, zn, wl, wcount, slots);
    rescue_fin<<<N_TOK / 256, 256, 0, stream>>>(flags, slots, idxf);
    epilogue_kernel<<<(ZST_ELEMS / 4) / 256, 256, 0, stream>>>(z, emb, idxf, zst, loss_accum);
    finalize_kernel<<<1, 1, 0, stream>>>(loss_accum, losses);
}